// Round 1
// baseline (326.987 us; speedup 1.0000x reference)
//
#include <hip/hip_runtime.h>
#include <math.h>

#define HEADS 4
#define CH 64
#define HC 256          // HEADS*CH
#define SLOPE 0.2f

typedef __attribute__((ext_vector_type(8))) short bf16x8;
typedef __attribute__((ext_vector_type(4))) float f32x4;

__device__ __forceinline__ float4 ld4(const float* p){ return *(const float4*)p; }
__device__ __forceinline__ void st4(float* p, float4 v){ *(float4*)p = v; }
__device__ __forceinline__ float lrelu(float x){ return x > 0.f ? x : SLOPE * x; }
__device__ __forceinline__ unsigned short f2bf(float f){
  union { float f; unsigned int u; } v; v.f = f;
  unsigned int r = v.u + 0x7fffu + ((v.u >> 16) & 1u);   // RNE
  return (unsigned short)(r >> 16);
}
__device__ __forceinline__ float bflo(unsigned int u){
  union { unsigned int u; float f; } v; v.u = u << 16; return v.f;
}
__device__ __forceinline__ float bfhi(unsigned int u){
  union { unsigned int u; float f; } v; v.u = u & 0xffff0000u; return v.f;
}
__device__ __forceinline__ void split2(float v, unsigned short& h, unsigned short& l){
  unsigned int u = __float_as_uint(v);
  h = (unsigned short)(u >> 16);
  float hf = __uint_as_float(u & 0xffff0000u);
  l = (unsigned short)(__float_as_uint(v - hf) >> 16);
}
// async global->LDS DMA, 16B/lane; LDS dest = wave-uniform base + lane*16
__device__ __forceinline__ void dma16(const unsigned short* g, unsigned short* l){
  __builtin_amdgcn_global_load_lds(
      (const __attribute__((address_space(1))) unsigned int*)g,
      (__attribute__((address_space(3))) unsigned int*)l, 16, 0, 0);
}

// ---------------- k_pre: splitA | split W/W1/W2 | degree count, one dispatch ----------------
// count[] zeroed by hipMemsetAsync before this dispatch; self-loop handled as +1 in scan.
__global__ __launch_bounds__(256) void k_pre(const float* __restrict__ x,
    const float* __restrict__ W, const float* __restrict__ W1, const float* __restrict__ W2,
    unsigned short* __restrict__ Ahi, unsigned short* __restrict__ Alo,
    unsigned short* __restrict__ Bhi, unsigned short* __restrict__ Blo,
    unsigned short* __restrict__ W1h, unsigned short* __restrict__ W1l,
    unsigned short* __restrict__ W2h, unsigned short* __restrict__ W2l,
    const int* __restrict__ ei, int* __restrict__ count,
    int nf4, int E, int nSplit) {
  int b = blockIdx.x, t = threadIdx.x;
  if (b < nSplit) {                         // splitA: x -> Ahi/Alo bf16
    int idx = b*256 + t;
    if (idx < nf4) {
      float4 v = ld4(&x[(size_t)idx*4]);
      ushort4 h, l;
      split2(v.x, h.x, l.x); split2(v.y, h.y, l.y);
      split2(v.z, h.z, l.z); split2(v.w, h.w, l.w);
      *(ushort4*)&Ahi[(size_t)idx*4] = h;
      *(ushort4*)&Alo[(size_t)idx*4] = l;
    }
  } else if (b < nSplit + 256) {            // W [256][256] -> [n][k]
    int nn = b - nSplit;
    unsigned short h, l;
    split2(W[(size_t)t*256 + nn], h, l);
    Bhi[(size_t)nn*256 + t] = h; Blo[(size_t)nn*256 + t] = l;
  } else if (b < nSplit + 320) {            // W1 [256][64] -> [n][k]
    int nn = b - nSplit - 256;
    unsigned short h, l;
    split2(W1[(size_t)t*64 + nn], h, l);
    W1h[(size_t)nn*256 + t] = h; W1l[(size_t)nn*256 + t] = l;
  } else if (b < nSplit + 368) {            // W2 [64][40] -> [n pad48][k64]
    if (t < 64) {
      int nn = b - nSplit - 320;
      float v = (nn < 40) ? W2[(size_t)t*40 + nn] : 0.f;
      unsigned short h, l;
      split2(v, h, l);
      W2h[(size_t)nn*64 + t] = h; W2l[(size_t)nn*64 + t] = l;
    }
  } else {                                  // degree count (edges only)
    int e = (b - nSplit - 368)*256 + t;
    if (e < E) atomicAdd(&count[ei[E+e]], 1);
  }
}

// ---------------- merged dispatch: GEMM1 (3-pass split-bf16 MFMA + attn dots) | scan1 ----------------
__global__ __launch_bounds__(256, 4) void k_gemmscan(const unsigned short* __restrict__ Ahi,
    const unsigned short* __restrict__ Alo,
    const unsigned short* __restrict__ Bhi_t, const unsigned short* __restrict__ Blo_t,
    unsigned short* __restrict__ hbf,
    const float* __restrict__ att_src, const float* __restrict__ att_dst,
    float* __restrict__ a_srcO, float* __restrict__ a_dstO, int M, int nGemm,
    const int* __restrict__ count, int* __restrict__ excl, int* __restrict__ partial, int n) {
  __shared__ __align__(16) unsigned short L[4*4096];  // gemm: Ah|Al|Bh|Bl; scan: int sd[256]
  int t = threadIdx.x;
  int b = blockIdx.x;
  if (b >= nGemm) {
    // ---- scan1: per-block exclusive scan of (count[i]+1) ----
    int* sd = (int*)L;
    int blk = b - nGemm;
    int i = blk*256 + t;
    int v = (i < n) ? count[i] + 1 : 0;
    sd[t] = v; __syncthreads();
    for (int off=1; off<256; off<<=1) {
      int xx = (t >= off) ? sd[t-off] : 0;
      __syncthreads();
      sd[t] += xx;
      __syncthreads();
    }
    if (i < n) excl[i] = sd[t] - v;
    if (t == 255) partial[blk] = sd[255];
    return;
  }
  int lane = t & 63, w = t >> 6;
  int wr = w >> 1, wc = w & 1;
  int ln15 = lane & 15, lq = lane >> 4;
  int row0 = (b >> 1) * 128, col0 = (b & 1) * 128;

  f32x4 acc[4][4];
  #pragma unroll
  for (int i=0;i<4;i++)
    #pragma unroll
    for (int j=0;j<4;j++) acc[i][j] = (f32x4){0.f,0.f,0.f,0.f};

  // DMA slot geometry (slot s: R=s>>3, u=(s&7)^(R&7) -> idx=2R|(u&1), seg=u>>1)
  int sA = w*128 + lane;
  int sB = sA + 64;
  int RA = sA>>3, uA = (sA&7)^(RA&7), idxA = (RA<<1)|(uA&1), segA = uA>>1;
  int RB = sB>>3, uB = (sB&7)^(RB&7), idxB = (RB<<1)|(uB&1), segB = uB>>1;
  size_t gA_a = (size_t)(row0+idxA)*256 + segA*8;
  size_t gA_b = (size_t)(row0+idxB)*256 + segB*8;
  size_t gB_a = (size_t)(col0+idxA)*256 + segA*8;
  size_t gB_b = (size_t)(col0+idxB)*256 + segB*8;
  int l0 = (w*128)*8, l1 = (w*128+64)*8;

  for (int c = 0; c < 8; c++) {
    int k0 = c*32;
    dma16(Ahi   + gA_a + k0, &L[0*4096 + l0]);
    dma16(Ahi   + gA_b + k0, &L[0*4096 + l1]);
    dma16(Alo   + gA_a + k0, &L[1*4096 + l0]);
    dma16(Alo   + gA_b + k0, &L[1*4096 + l1]);
    dma16(Bhi_t + gB_a + k0, &L[2*4096 + l0]);
    dma16(Bhi_t + gB_b + k0, &L[2*4096 + l1]);
    dma16(Blo_t + gB_a + k0, &L[3*4096 + l0]);
    dma16(Blo_t + gB_b + k0, &L[3*4096 + l1]);
    __syncthreads();

    bf16x8 bh[4], bl[4];
    #pragma unroll
    for (int j = 0; j < 4; j++) {
      int nn = wc*64 + j*16 + ln15;
      int R = nn >> 1, u = (lq << 1) | (nn & 1);
      int s = R*8 + (u ^ (R & 7));
      bh[j] = *(bf16x8*)&L[2*4096 + s*8];
      bl[j] = *(bf16x8*)&L[3*4096 + s*8];
    }
    #pragma unroll
    for (int i = 0; i < 4; i++) {
      int r = wr*64 + i*16 + ln15;
      int R = r >> 1, u = (lq << 1) | (r & 1);
      int s = R*8 + (u ^ (R & 7));
      bf16x8 ah = *(bf16x8*)&L[0*4096 + s*8];
      bf16x8 al = *(bf16x8*)&L[1*4096 + s*8];
      #pragma unroll
      for (int j = 0; j < 4; j++) {
        acc[i][j] = __builtin_amdgcn_mfma_f32_16x16x32_bf16(ah, bh[j], acc[i][j], 0,0,0);
        acc[i][j] = __builtin_amdgcn_mfma_f32_16x16x32_bf16(al, bh[j], acc[i][j], 0,0,0);
        acc[i][j] = __builtin_amdgcn_mfma_f32_16x16x32_bf16(ah, bl[j], acc[i][j], 0,0,0);
      }
    }
    __syncthreads();
  }
  // ---- epilogue: store h bf16 (C/D: col=lane&15, row=(lane>>4)*4+reg) ----
  #pragma unroll
  for (int i = 0; i < 4; i++) {
    #pragma unroll
    for (int r = 0; r < 4; r++) {
      int row = row0 + wr*64 + i*16 + lq*4 + r;
      if (row < M) {
        #pragma unroll
        for (int j = 0; j < 4; j++) {
          int col = col0 + wc*64 + j*16 + ln15;
          hbf[(size_t)row*HC + col] = f2bf(acc[i][j][r]);
        }
      }
    }
  }
  // ---- fused attention dots: this wave's 64 cols == head ----
  int head = (b & 1)*2 + wc;
  float asv[4], adv[4];
  #pragma unroll
  for (int j=0;j<4;j++){
    asv[j] = att_src[head*CH + j*16 + ln15];
    adv[j] = att_dst[head*CH + j*16 + ln15];
  }
  #pragma unroll
  for (int i = 0; i < 4; i++) {
    #pragma unroll
    for (int r = 0; r < 4; r++) {
      float ps = acc[i][0][r]*asv[0] + acc[i][1][r]*asv[1]
               + acc[i][2][r]*asv[2] + acc[i][3][r]*asv[3];
      float pd = acc[i][0][r]*adv[0] + acc[i][1][r]*adv[1]
               + acc[i][2][r]*adv[2] + acc[i][3][r]*adv[3];
      #pragma unroll
      for (int m=8; m>=1; m>>=1) { ps += __shfl_xor(ps, m); pd += __shfl_xor(pd, m); }
      if (ln15 == 0) {
        int row = row0 + wr*64 + i*16 + lq*4 + r;
        if (row < M) { a_srcO[row*4+head] = ps; a_dstO[row*4+head] = pd; }
      }
    }
  }
}

// ---------------- scan2+scan3 merged ----------------
__global__ __launch_bounds__(256) void k_scan23(int* __restrict__ row_start,
    int* __restrict__ cursor, const int* __restrict__ partial,
    const int* __restrict__ count, int n, int nb) {
  __shared__ int sd[256];
  int b = blockIdx.x, t = threadIdx.x;
  int v = (t < nb) ? partial[t] : 0;
  sd[t] = v; __syncthreads();
  for (int off=1; off<256; off<<=1) {
    int xx = (t >= off) ? sd[t-off] : 0;
    __syncthreads();
    sd[t] += xx;
    __syncthreads();
  }
  int pb = (b > 0) ? sd[b-1] : 0;
  int i = b*256 + t;
  if (i < n) {
    int vv = row_start[i] + pb;
    row_start[i] = vv;
    cursor[i] = vv;
    if (i == n-1) row_start[n] = vv + count[i] + 1;
  }
}

__global__ void k_fill(const int* __restrict__ ei, int* __restrict__ cursor,
    int* __restrict__ csr, int E, int n) {
  int t = blockIdx.x*256 + threadIdx.x;
  if (t < E + n) {
    int s, d;
    if (t < E) { s = ei[t]; d = ei[E+t]; } else { s = t - E; d = s; }
    int p = atomicAdd(&cursor[d], 1);
    csr[p] = s;
  }
}

// ---------------- GAT softmax + aggregate, one WAVE per dst node; bf16 out ----------------
// No max-subtraction: logits bounded (|e| << 80), softmax shift-invariant.
// Latency-bound -> 4-deep gather pipeline (8 edges/iter, 4 uint4 in flight per lane).
// Denominator: each lane sums the s_p[edge][hd8] values it already reads for the FMA
// (covers all edges of its half) -> one xor32 shuffle replaces the 64-lane butterfly.
__global__ __launch_bounds__(256) void k_gat(const unsigned short* __restrict__ hbf,
    const float4* __restrict__ a_src, const float4* __restrict__ a_dst,
    const int* __restrict__ row_start, const int* __restrict__ csr,
    const float* __restrict__ bias, unsigned short* __restrict__ outbf) {
  int w = threadIdx.x >> 6, lane = threadIdx.x & 63;
  int n = blockIdx.x * 4 + w;          // grid = N/4 exactly
  int half = lane >> 5, cl = lane & 31;
  int c0 = cl * 8;
  int hd8 = cl >> 3;

  __shared__ float s_p[4][64][4];      // [wave][edge][head]

  float4 ad = a_dst[n];
  float dsum = 0.f;
  float acc[8];
  #pragma unroll
  for (int k=0;k<8;k++) acc[k]=0.f;

  int beg = row_start[n];
  int deg = row_start[n+1] - beg;

  for (int cb = 0; cb < deg; cb += 64) {
    int cnt = min(64, deg - cb);
    int s = 0;
    float4 p = make_float4(0.f,0.f,0.f,0.f);
    if (lane < cnt) {
      s = csr[beg + cb + lane];
      float4 as = a_src[s];
      p.x = __expf(lrelu(as.x + ad.x));
      p.y = __expf(lrelu(as.y + ad.y));
      p.z = __expf(lrelu(as.z + ad.z));
      p.w = __expf(lrelu(as.w + ad.w));
    }
    st4(&s_p[w][lane][0], p);          // wave-local (no barrier needed)

    // group q covers edges {q8+half, q8+2+half, q8+4+half, q8+6+half}; prefetch q+1.
    // loop trip count is wave-uniform (q8 from cnt only) so __shfl stays converged.
    bool v0 = (half + 0) < cnt, v1 = (half + 2) < cnt,
         v2 = (half + 4) < cnt, v3 = (half + 6) < cnt;
    uint4 u0 = make_uint4(0,0,0,0), u1 = u0, u2 = u0, u3 = u0;
    int ss;
    ss = __shfl(s, half + 0); if (v0) u0 = *(const uint4*)&hbf[(size_t)ss*HC + c0];
    ss = __shfl(s, half + 2); if (v1) u1 = *(const uint4*)&hbf[(size_t)ss*HC + c0];
    ss = __shfl(s, half + 4); if (v2) u2 = *(const uint4*)&hbf[(size_t)ss*HC + c0];
    ss = __shfl(s, half + 6); if (v3) u3 = *(const uint4*)&hbf[(size_t)ss*HC + c0];
    for (int q8 = 0; q8 < cnt; q8 += 8) {
      int b0 = q8 + half;
      int f0 = b0 + 8, f1 = b0 + 10, f2 = b0 + 12, f3 = b0 + 14;
      bool w0 = f0 < cnt, w1 = f1 < cnt, w2 = f2 < cnt, w3 = f3 < cnt;
      uint4 t0 = make_uint4(0,0,0,0), t1 = t0, t2 = t0, t3 = t0;
      ss = __shfl(s, f0 & 63); if (w0) t0 = *(const uint4*)&hbf[(size_t)ss*HC + c0];
      ss = __shfl(s, f1 & 63); if (w1) t1 = *(const uint4*)&hbf[(size_t)ss*HC + c0];
      ss = __shfl(s, f2 & 63); if (w2) t2 = *(const uint4*)&hbf[(size_t)ss*HC + c0];
      ss = __shfl(s, f3 & 63); if (w3) t3 = *(const uint4*)&hbf[(size_t)ss*HC + c0];
      if (v0) {
        float pw = s_p[w][b0    ][hd8]; dsum += pw;
        acc[0] += pw*bflo(u0.x); acc[1] += pw*bfhi(u0.x);
        acc[2] += pw*bflo(u0.y); acc[3] += pw*bfhi(u0.y);
        acc[4] += pw*bflo(u0.z); acc[5] += pw*bfhi(u0.z);
        acc[6] += pw*bflo(u0.w); acc[7] += pw*bfhi(u0.w);
      }
      if (v1) {
        float pw = s_p[w][b0 + 2][hd8]; dsum += pw;
        acc[0] += pw*bflo(u1.x); acc[1] += pw*bfhi(u1.x);
        acc[2] += pw*bflo(u1.y); acc[3] += pw*bfhi(u1.y);
        acc[4] += pw*bflo(u1.z); acc[5] += pw*bfhi(u1.z);
        acc[6] += pw*bflo(u1.w); acc[7] += pw*bfhi(u1.w);
      }
      if (v2) {
        float pw = s_p[w][b0 + 4][hd8]; dsum += pw;
        acc[0] += pw*bflo(u2.x); acc[1] += pw*bfhi(u2.x);
        acc[2] += pw*bflo(u2.y); acc[3] += pw*bfhi(u2.y);
        acc[4] += pw*bflo(u2.z); acc[5] += pw*bfhi(u2.z);
        acc[6] += pw*bflo(u2.w); acc[7] += pw*bfhi(u2.w);
      }
      if (v3) {
        float pw = s_p[w][b0 + 6][hd8]; dsum += pw;
        acc[0] += pw*bflo(u3.x); acc[1] += pw*bfhi(u3.x);
        acc[2] += pw*bflo(u3.y); acc[3] += pw*bfhi(u3.y);
        acc[4] += pw*bflo(u3.z); acc[5] += pw*bfhi(u3.z);
        acc[6] += pw*bflo(u3.w); acc[7] += pw*bfhi(u3.w);
      }
      u0 = t0; u1 = t1; u2 = t2; u3 = t3;
      v0 = w0; v1 = w1; v2 = w2; v3 = w3;
    }
  }
  // cross-half combine: dsum(lane) holds sum over its half's edges for head hd8
  dsum += __shfl_xor(dsum, 32);
  #pragma unroll
  for (int k=0;k<8;k++) acc[k] += __shfl_xor(acc[k], 32);
  float inv = 1.f / dsum;
  int kb = half * 4;
  float4 b = ld4(&bias[c0 + kb]);
  ushort4 o;
  o.x = f2bf(fmaxf(acc[kb+0]*inv + b.x, 0.f));
  o.y = f2bf(fmaxf(acc[kb+1]*inv + b.y, 0.f));
  o.z = f2bf(fmaxf(acc[kb+2]*inv + b.z, 0.f));
  o.w = f2bf(fmaxf(acc[kb+3]*inv + b.w, 0.f));
  *(ushort4*)&outbf[(size_t)n*HC + c0 + kb] = o;
}

// ---------------- fused MLP: out = relu(Cbf@W1+b1)@W2+b2, MFMA ----------------
__global__ __launch_bounds__(256) void k_mlp(const unsigned short* __restrict__ Cbf,
    const unsigned short* __restrict__ W1h, const unsigned short* __restrict__ W1l,
    const unsigned short* __restrict__ W2h, const unsigned short* __restrict__ W2l,
    const float* __restrict__ b1, const float* __restrict__ b2,
    float* __restrict__ out, int M) {
  __shared__ __align__(16) unsigned short Abuf[4096];   // 128 rows x 32 k (slot-swizzled)
  __shared__ __align__(16) unsigned short Hs[128*72];   // hid bf16, stride 72
  int t = threadIdx.x, lane = t & 63, w = t >> 6;
  int ln15 = lane & 15, lq = lane >> 4;
  int row0 = blockIdx.x * 128;

  f32x4 acc1[2][4];
  #pragma unroll
  for (int i=0;i<2;i++)
    #pragma unroll
    for (int j=0;j<4;j++) acc1[i][j] = (f32x4){0.f,0.f,0.f,0.f};

  int sA = w*64 + lane;
  int sB = 256 + w*64 + lane;
  int rA = sA >> 2, segA = (sA & 3) ^ ((rA >> 1) & 3);
  int rB = sB >> 2, segB = (sB & 3) ^ ((rB >> 1) & 3);
  size_t gA = (size_t)(row0 + rA) * 256 + segA*8;
  size_t gB = (size_t)(row0 + rB) * 256 + segB*8;
  int lA = (w*64)*8, lB = (256 + w*64)*8;

  for (int c = 0; c < 8; c++) {
    int k0 = c*32;
    dma16(Cbf + gA + k0, &Abuf[lA]);
    dma16(Cbf + gB + k0, &Abuf[lB]);
    __syncthreads();
    bf16x8 a[2];
    #pragma unroll
    for (int i = 0; i < 2; i++) {
      int r = w*32 + i*16 + ln15;
      int s = r*4 + (lq ^ ((r >> 1) & 3));
      a[i] = *(bf16x8*)&Abuf[s*8];
    }
    #pragma unroll
    for (int j = 0; j < 4; j++) {
      int n = j*16 + ln15;
      int k = k0 + lq*8;
      bf16x8 bh = *(const bf16x8*)&W1h[(size_t)n*256 + k];
      bf16x8 bl = *(const bf16x8*)&W1l[(size_t)n*256 + k];
      #pragma unroll
      for (int i = 0; i < 2; i++) {
        acc1[i][j] = __builtin_amdgcn_mfma_f32_16x16x32_bf16(a[i], bh, acc1[i][j], 0,0,0);
        acc1[i][j] = __builtin_amdgcn_mfma_f32_16x16x32_bf16(a[i], bl, acc1[i][j], 0,0,0);
      }
    }
    __syncthreads();
  }
  #pragma unroll
  for (int j = 0; j < 4; j++) {
    int col = j*16 + ln15;
    float bv = b1[col];
    #pragma unroll
    for (int i = 0; i < 2; i++) {
      #pragma unroll
      for (int r = 0; r < 4; r++) {
        int row = w*32 + i*16 + lq*4 + r;
        Hs[row*72 + col] = f2bf(fmaxf(acc1[i][j][r] + bv, 0.f));
      }
    }
  }
  f32x4 acc2[2][3];
  #pragma unroll
  for (int i=0;i<2;i++)
    #pragma unroll
    for (int j=0;j<3;j++) acc2[i][j] = (f32x4){0.f,0.f,0.f,0.f};
  #pragma unroll
  for (int kf = 0; kf < 2; kf++) {
    bf16x8 a2[2];
    #pragma unroll
    for (int i = 0; i < 2; i++) {
      int m = w*32 + i*16 + ln15;
      a2[i] = *(bf16x8*)&Hs[m*72 + kf*32 + lq*8];
    }
    #pragma unroll
    for (int j = 0; j < 3; j++) {
      int n = j*16 + ln15;
      int k = kf*32 + lq*8;
      bf16x8 wh = *(const bf16x8*)&W2h[(size_t)n*64 + k];
      bf16x8 wl = *(const bf16x8*)&W2l[(size_t)n*64 + k];
      #pragma unroll
      for (int i = 0; i < 2; i++) {
        acc2[i][j] = __builtin_amdgcn_mfma_f32_16x16x32_bf16(a2[i], wh, acc2[i][j], 0,0,0);
        acc2[i][j] = __builtin_amdgcn_mfma_f32_16x16x32_bf16(a2[i], wl, acc2[i][j], 0,0,0);
      }
    }
  }
  #pragma unroll
  for (int j = 0; j < 3; j++) {
    int col = j*16 + ln15;
    if (col < 40) {
      float bv = b2[col];
      #pragma unroll
      for (int i = 0; i < 2; i++) {
        #pragma unroll
        for (int r = 0; r < 4; r++) {
          int row = row0 + w*32 + i*16 + lq*4 + r;
          if (row < M) out[(size_t)row*40 + col] = acc2[i][j][r] + bv;
        }
      }
    }
  }
}

extern "C" void kernel_launch(void* const* d_in, const int* in_sizes, int n_in,
                              void* d_out, int out_size, void* d_ws, size_t ws_size,
                              hipStream_t stream) {
  const int Nn = in_sizes[0] / HC;   // 50000
  const int E  = in_sizes[1] / 2;    // 800000
  const int Mpad = (Nn + 127) & ~127;
  const float* x        = (const float*)d_in[0];
  const int*   ei       = (const int*)d_in[1];
  const float* W        = (const float*)d_in[2];
  const float* att_src  = (const float*)d_in[3];
  const float* att_dst  = (const float*)d_in[4];
  const float* biasconv = (const float*)d_in[5];
  const float* W1       = (const float*)d_in[6];
  const float* b1       = (const float*)d_in[7];
  const float* W2       = (const float*)d_in[8];
  const float* b2       = (const float*)d_in[9];
  float* out = (float*)d_out;

  size_t off = 0;
  auto alloc = [&](size_t bytes)->void* {
    void* p = (void*)((char*)d_ws + off);
    off += (bytes + 255) & ~(size_t)255;
    return p;
  };
  unsigned short* hbf = (unsigned short*)alloc((size_t)Nn*HC*sizeof(unsigned short));
  void* ublk = alloc((size_t)Mpad*HC*sizeof(float));
  unsigned short* Ahi = (unsigned short*)ublk;
  unsigned short* Alo = Ahi + (size_t)Mpad*HC;
  unsigned short* outc = (unsigned short*)ublk;    // aliases Ahi/Alo (disjoint lifetime)
  unsigned short* Bhi = (unsigned short*)alloc((size_t)256*256*sizeof(unsigned short));
  unsigned short* Blo = (unsigned short*)alloc((size_t)256*256*sizeof(unsigned short));
  unsigned short* W1h = (unsigned short*)alloc((size_t)64*256*sizeof(unsigned short));
  unsigned short* W1l = (unsigned short*)alloc((size_t)64*256*sizeof(unsigned short));
  unsigned short* W2h = (unsigned short*)alloc((size_t)48*64*sizeof(unsigned short));
  unsigned short* W2l = (unsigned short*)alloc((size_t)48*64*sizeof(unsigned short));
  float* a_src_v  = (float*)alloc((size_t)Nn*4*sizeof(float));
  float* a_dst_v  = (float*)alloc((size_t)Nn*4*sizeof(float));
  int*   count    = (int*)alloc((size_t)Nn*sizeof(int));
  int*   rowstart = (int*)alloc((size_t)(Nn+1)*sizeof(int));
  int*   cursor   = (int*)alloc((size_t)Nn*sizeof(int));
  int*   partial  = (int*)alloc(256*sizeof(int));
  int*   csr      = (int*)alloc((size_t)(E+Nn)*sizeof(int));
  (void)ws_size; (void)n_in; (void)out_size;

  dim3 blk(256);
  int nf4 = Nn*64;
  int nSplit = (nf4 + 255)/256;
  int nCnt = (E + 255)/256;
  int nb = (Nn + 255)/256;
  int nGemm = 2 * (Mpad/128);

  hipMemsetAsync(count, 0, (size_t)Nn*sizeof(int), stream);
  k_pre<<<dim3(nSplit + 368 + nCnt), blk, 0, stream>>>(x, W, W1, W2,
      Ahi, Alo, Bhi, Blo, W1h, W1l, W2h, W2l, ei, count, nf4, E, nSplit);
  k_gemmscan<<<dim3(nGemm + nb), blk, 0, stream>>>(Ahi, Alo, Bhi, Blo, hbf,
      att_src, att_dst, a_src_v, a_dst_v, Nn, nGemm, count, rowstart, partial, Nn);
  k_scan23<<<dim3(nb), blk, 0, stream>>>(rowstart, cursor, partial, count, Nn, nb);
  k_fill<<<dim3((E+Nn+255)/256), blk, 0, stream>>>(ei, cursor, csr, E, Nn);
  k_gat<<<dim3(Nn/4), blk, 0, stream>>>(hbf, (const float4*)a_src_v, (const float4*)a_dst_v,
                                        rowstart, csr, biasconv, outc);
  k_mlp<<<dim3(Mpad/128), blk, 0, stream>>>(outc, W1h, W1l, W2h, W2l, b1, b2, out, Nn);
}

// Round 2
// 326.870 us; speedup vs baseline: 1.0004x; 1.0004x over previous
//
#include <hip/hip_runtime.h>
#include <math.h>

#define HEADS 4
#define CH 64
#define HC 256          // HEADS*CH
#define SLOPE 0.2f

typedef __attribute__((ext_vector_type(8))) short bf16x8;
typedef __attribute__((ext_vector_type(4))) float f32x4;

__device__ __forceinline__ float4 ld4(const float* p){ return *(const float4*)p; }
__device__ __forceinline__ void st4(float* p, float4 v){ *(float4*)p = v; }
__device__ __forceinline__ float lrelu(float x){ return x > 0.f ? x : SLOPE * x; }
__device__ __forceinline__ unsigned short f2bf(float f){
  union { float f; unsigned int u; } v; v.f = f;
  unsigned int r = v.u + 0x7fffu + ((v.u >> 16) & 1u);   // RNE
  return (unsigned short)(r >> 16);
}
__device__ __forceinline__ float bflo(unsigned int u){
  union { unsigned int u; float f; } v; v.u = u << 16; return v.f;
}
__device__ __forceinline__ float bfhi(unsigned int u){
  union { unsigned int u; float f; } v; v.u = u & 0xffff0000u; return v.f;
}
__device__ __forceinline__ void split2(float v, unsigned short& h, unsigned short& l){
  unsigned int u = __float_as_uint(v);
  h = (unsigned short)(u >> 16);
  float hf = __uint_as_float(u & 0xffff0000u);
  l = (unsigned short)(__float_as_uint(v - hf) >> 16);
}
// async global->LDS DMA, 16B/lane; LDS dest = wave-uniform base + lane*16
__device__ __forceinline__ void dma16(const unsigned short* g, unsigned short* l){
  __builtin_amdgcn_global_load_lds(
      (const __attribute__((address_space(1))) unsigned int*)g,
      (__attribute__((address_space(3))) unsigned int*)l, 16, 0, 0);
}

// ---------------- k_pre: splitA | split W/W1/W2 | degree count, one dispatch ----------------
// count[] zeroed by hipMemsetAsync before this dispatch; self-loop handled as +1 in scan.
__global__ __launch_bounds__(256) void k_pre(const float* __restrict__ x,
    const float* __restrict__ W, const float* __restrict__ W1, const float* __restrict__ W2,
    unsigned short* __restrict__ Ahi, unsigned short* __restrict__ Alo,
    unsigned short* __restrict__ Bhi, unsigned short* __restrict__ Blo,
    unsigned short* __restrict__ W1h, unsigned short* __restrict__ W1l,
    unsigned short* __restrict__ W2h, unsigned short* __restrict__ W2l,
    const int* __restrict__ ei, int* __restrict__ count,
    int nf4, int E, int nSplit) {
  int b = blockIdx.x, t = threadIdx.x;
  if (b < nSplit) {                         // splitA: x -> Ahi/Alo bf16
    int idx = b*256 + t;
    if (idx < nf4) {
      float4 v = ld4(&x[(size_t)idx*4]);
      ushort4 h, l;
      split2(v.x, h.x, l.x); split2(v.y, h.y, l.y);
      split2(v.z, h.z, l.z); split2(v.w, h.w, l.w);
      *(ushort4*)&Ahi[(size_t)idx*4] = h;
      *(ushort4*)&Alo[(size_t)idx*4] = l;
    }
  } else if (b < nSplit + 256) {            // W [256][256] -> [n][k]
    int nn = b - nSplit;
    unsigned short h, l;
    split2(W[(size_t)t*256 + nn], h, l);
    Bhi[(size_t)nn*256 + t] = h; Blo[(size_t)nn*256 + t] = l;
  } else if (b < nSplit + 320) {            // W1 [256][64] -> [n][k]
    int nn = b - nSplit - 256;
    unsigned short h, l;
    split2(W1[(size_t)t*64 + nn], h, l);
    W1h[(size_t)nn*256 + t] = h; W1l[(size_t)nn*256 + t] = l;
  } else if (b < nSplit + 368) {            // W2 [64][40] -> [n pad48][k64]
    if (t < 64) {
      int nn = b - nSplit - 320;
      float v = (nn < 40) ? W2[(size_t)t*40 + nn] : 0.f;
      unsigned short h, l;
      split2(v, h, l);
      W2h[(size_t)nn*64 + t] = h; W2l[(size_t)nn*64 + t] = l;
    }
  } else {                                  // degree count (edges only)
    int e = (b - nSplit - 368)*256 + t;
    if (e < E) atomicAdd(&count[ei[E+e]], 1);
  }
}

// ---------------- merged dispatch: GEMM1 (3-pass split-bf16 MFMA + attn dots) | scan1 ----------------
__global__ __launch_bounds__(256, 4) void k_gemmscan(const unsigned short* __restrict__ Ahi,
    const unsigned short* __restrict__ Alo,
    const unsigned short* __restrict__ Bhi_t, const unsigned short* __restrict__ Blo_t,
    unsigned short* __restrict__ hbf,
    const float* __restrict__ att_src, const float* __restrict__ att_dst,
    float* __restrict__ a_srcO, float* __restrict__ a_dstO, int M, int nGemm,
    const int* __restrict__ count, int* __restrict__ excl, int* __restrict__ partial, int n) {
  __shared__ __align__(16) unsigned short L[4*4096];  // gemm: Ah|Al|Bh|Bl; scan: int sd[256]
  int t = threadIdx.x;
  int b = blockIdx.x;
  if (b >= nGemm) {
    // ---- scan1: per-block exclusive scan of (count[i]+1) ----
    int* sd = (int*)L;
    int blk = b - nGemm;
    int i = blk*256 + t;
    int v = (i < n) ? count[i] + 1 : 0;
    sd[t] = v; __syncthreads();
    for (int off=1; off<256; off<<=1) {
      int xx = (t >= off) ? sd[t-off] : 0;
      __syncthreads();
      sd[t] += xx;
      __syncthreads();
    }
    if (i < n) excl[i] = sd[t] - v;
    if (t == 255) partial[blk] = sd[255];
    return;
  }
  int lane = t & 63, w = t >> 6;
  int wr = w >> 1, wc = w & 1;
  int ln15 = lane & 15, lq = lane >> 4;
  int row0 = (b >> 1) * 128, col0 = (b & 1) * 128;

  f32x4 acc[4][4];
  #pragma unroll
  for (int i=0;i<4;i++)
    #pragma unroll
    for (int j=0;j<4;j++) acc[i][j] = (f32x4){0.f,0.f,0.f,0.f};

  // DMA slot geometry (slot s: R=s>>3, u=(s&7)^(R&7) -> idx=2R|(u&1), seg=u>>1)
  int sA = w*128 + lane;
  int sB = sA + 64;
  int RA = sA>>3, uA = (sA&7)^(RA&7), idxA = (RA<<1)|(uA&1), segA = uA>>1;
  int RB = sB>>3, uB = (sB&7)^(RB&7), idxB = (RB<<1)|(uB&1), segB = uB>>1;
  size_t gA_a = (size_t)(row0+idxA)*256 + segA*8;
  size_t gA_b = (size_t)(row0+idxB)*256 + segB*8;
  size_t gB_a = (size_t)(col0+idxA)*256 + segA*8;
  size_t gB_b = (size_t)(col0+idxB)*256 + segB*8;
  int l0 = (w*128)*8, l1 = (w*128+64)*8;

  for (int c = 0; c < 8; c++) {
    int k0 = c*32;
    dma16(Ahi   + gA_a + k0, &L[0*4096 + l0]);
    dma16(Ahi   + gA_b + k0, &L[0*4096 + l1]);
    dma16(Alo   + gA_a + k0, &L[1*4096 + l0]);
    dma16(Alo   + gA_b + k0, &L[1*4096 + l1]);
    dma16(Bhi_t + gB_a + k0, &L[2*4096 + l0]);
    dma16(Bhi_t + gB_b + k0, &L[2*4096 + l1]);
    dma16(Blo_t + gB_a + k0, &L[3*4096 + l0]);
    dma16(Blo_t + gB_b + k0, &L[3*4096 + l1]);
    __syncthreads();

    bf16x8 bh[4], bl[4];
    #pragma unroll
    for (int j = 0; j < 4; j++) {
      int nn = wc*64 + j*16 + ln15;
      int R = nn >> 1, u = (lq << 1) | (nn & 1);
      int s = R*8 + (u ^ (R & 7));
      bh[j] = *(bf16x8*)&L[2*4096 + s*8];
      bl[j] = *(bf16x8*)&L[3*4096 + s*8];
    }
    #pragma unroll
    for (int i = 0; i < 4; i++) {
      int r = wr*64 + i*16 + ln15;
      int R = r >> 1, u = (lq << 1) | (r & 1);
      int s = R*8 + (u ^ (R & 7));
      bf16x8 ah = *(bf16x8*)&L[0*4096 + s*8];
      bf16x8 al = *(bf16x8*)&L[1*4096 + s*8];
      #pragma unroll
      for (int j = 0; j < 4; j++) {
        acc[i][j] = __builtin_amdgcn_mfma_f32_16x16x32_bf16(ah, bh[j], acc[i][j], 0,0,0);
        acc[i][j] = __builtin_amdgcn_mfma_f32_16x16x32_bf16(al, bh[j], acc[i][j], 0,0,0);
        acc[i][j] = __builtin_amdgcn_mfma_f32_16x16x32_bf16(ah, bl[j], acc[i][j], 0,0,0);
      }
    }
    __syncthreads();
  }
  // ---- epilogue: store h bf16 (C/D: col=lane&15, row=(lane>>4)*4+reg) ----
  #pragma unroll
  for (int i = 0; i < 4; i++) {
    #pragma unroll
    for (int r = 0; r < 4; r++) {
      int row = row0 + wr*64 + i*16 + lq*4 + r;
      if (row < M) {
        #pragma unroll
        for (int j = 0; j < 4; j++) {
          int col = col0 + wc*64 + j*16 + ln15;
          hbf[(size_t)row*HC + col] = f2bf(acc[i][j][r]);
        }
      }
    }
  }
  // ---- fused attention dots: this wave's 64 cols == head ----
  int head = (b & 1)*2 + wc;
  float asv[4], adv[4];
  #pragma unroll
  for (int j=0;j<4;j++){
    asv[j] = att_src[head*CH + j*16 + ln15];
    adv[j] = att_dst[head*CH + j*16 + ln15];
  }
  #pragma unroll
  for (int i = 0; i < 4; i++) {
    #pragma unroll
    for (int r = 0; r < 4; r++) {
      float ps = acc[i][0][r]*asv[0] + acc[i][1][r]*asv[1]
               + acc[i][2][r]*asv[2] + acc[i][3][r]*asv[3];
      float pd = acc[i][0][r]*adv[0] + acc[i][1][r]*adv[1]
               + acc[i][2][r]*adv[2] + acc[i][3][r]*adv[3];
      #pragma unroll
      for (int m=8; m>=1; m>>=1) { ps += __shfl_xor(ps, m); pd += __shfl_xor(pd, m); }
      if (ln15 == 0) {
        int row = row0 + wr*64 + i*16 + lq*4 + r;
        if (row < M) { a_srcO[row*4+head] = ps; a_dstO[row*4+head] = pd; }
      }
    }
  }
}

// ---------------- scan2+scan3 merged ----------------
__global__ __launch_bounds__(256) void k_scan23(int* __restrict__ row_start,
    int* __restrict__ cursor, const int* __restrict__ partial,
    const int* __restrict__ count, int n, int nb) {
  __shared__ int sd[256];
  int b = blockIdx.x, t = threadIdx.x;
  int v = (t < nb) ? partial[t] : 0;
  sd[t] = v; __syncthreads();
  for (int off=1; off<256; off<<=1) {
    int xx = (t >= off) ? sd[t-off] : 0;
    __syncthreads();
    sd[t] += xx;
    __syncthreads();
  }
  int pb = (b > 0) ? sd[b-1] : 0;
  int i = b*256 + t;
  if (i < n) {
    int vv = row_start[i] + pb;
    row_start[i] = vv;
    cursor[i] = vv;
    if (i == n-1) row_start[n] = vv + count[i] + 1;
  }
}

__global__ void k_fill(const int* __restrict__ ei, int* __restrict__ cursor,
    int* __restrict__ csr, int E, int n) {
  int t = blockIdx.x*256 + threadIdx.x;
  if (t < E + n) {
    int s, d;
    if (t < E) { s = ei[t]; d = ei[E+t]; } else { s = t - E; d = s; }
    int p = atomicAdd(&cursor[d], 1);
    csr[p] = s;
  }
}

// ---------------- GAT softmax + aggregate: one 32-lane HALF per dst node; bf16 out ----------------
// No max-subtraction: logits bounded (|e| << 80), softmax shift-invariant.
// 2 nodes/wave (one per half): each half gathers its node's full 512B h-row
// (32 lanes x 16B), keeps a lane-local denominator (no cross-half combine),
// and runs a 4-deep gather pipeline (wave total: 4 x 1KB loads in flight).
__global__ __launch_bounds__(256) void k_gat(const unsigned short* __restrict__ hbf,
    const float4* __restrict__ a_src, const float4* __restrict__ a_dst,
    const int* __restrict__ row_start, const int* __restrict__ csr,
    const float* __restrict__ bias, unsigned short* __restrict__ outbf) {
  int w = threadIdx.x >> 6, lane = threadIdx.x & 63;
  int half = lane >> 5, cl = lane & 31;
  int n = blockIdx.x * 8 + w * 2 + half;   // grid = N/8 exactly
  int c0 = cl * 8;                          // this lane's 8 channels
  int hd8 = cl >> 3;                        // head of those channels
  int eb = half * 32;                       // this half's s_p slot base

  __shared__ float s_p[4][64][4];           // [wave][edge slot][head]

  float4 ad = a_dst[n];
  float dsum = 0.f;
  float acc[8];
  #pragma unroll
  for (int k=0;k<8;k++) acc[k]=0.f;

  int beg = row_start[n];
  int deg = row_start[n+1] - beg;
  int degmax = max(deg, __shfl_xor(deg, 32));   // wave-uniform outer trip count

  for (int cb = 0; cb < degmax; cb += 32) {
    int cnt = min(32, deg - cb);              // per-half (may be <= 0)
    int cntmax = min(32, degmax - cb);        // wave-uniform inner trip count
    int s = 0;
    float4 p = make_float4(0.f,0.f,0.f,0.f);
    if (cl < cnt) {
      s = csr[beg + cb + cl];
      float4 as = a_src[s];
      p.x = __expf(lrelu(as.x + ad.x));
      p.y = __expf(lrelu(as.y + ad.y));
      p.z = __expf(lrelu(as.z + ad.z));
      p.w = __expf(lrelu(as.w + ad.w));
    }
    st4(&s_p[w][eb + cl][0], p);              // wave-local (no barrier needed)

    // 4-deep pipeline: group g covers edges {g4..g4+3} of this half; prefetch g+1.
    bool v0 = 0 < cnt, v1 = 1 < cnt, v2 = 2 < cnt, v3 = 3 < cnt;
    uint4 u0 = make_uint4(0,0,0,0), u1 = u0, u2 = u0, u3 = u0;
    int ss;
    ss = __shfl(s, eb + 0); if (v0) u0 = *(const uint4*)&hbf[(size_t)ss*HC + c0];
    ss = __shfl(s, eb + 1); if (v1) u1 = *(const uint4*)&hbf[(size_t)ss*HC + c0];
    ss = __shfl(s, eb + 2); if (v2) u2 = *(const uint4*)&hbf[(size_t)ss*HC + c0];
    ss = __shfl(s, eb + 3); if (v3) u3 = *(const uint4*)&hbf[(size_t)ss*HC + c0];
    for (int g4 = 0; g4 < cntmax; g4 += 4) {
      int f0 = g4+4, f1 = g4+5, f2 = g4+6, f3 = g4+7;
      bool w0 = f0 < cnt, w1 = f1 < cnt, w2 = f2 < cnt, w3 = f3 < cnt;
      uint4 t0 = make_uint4(0,0,0,0), t1 = t0, t2 = t0, t3 = t0;
      ss = __shfl(s, eb + (f0 & 31)); if (w0) t0 = *(const uint4*)&hbf[(size_t)ss*HC + c0];
      ss = __shfl(s, eb + (f1 & 31)); if (w1) t1 = *(const uint4*)&hbf[(size_t)ss*HC + c0];
      ss = __shfl(s, eb + (f2 & 31)); if (w2) t2 = *(const uint4*)&hbf[(size_t)ss*HC + c0];
      ss = __shfl(s, eb + (f3 & 31)); if (w3) t3 = *(const uint4*)&hbf[(size_t)ss*HC + c0];
      if (v0) {
        float pw = s_p[w][eb + g4    ][hd8]; dsum += pw;
        acc[0] += pw*bflo(u0.x); acc[1] += pw*bfhi(u0.x);
        acc[2] += pw*bflo(u0.y); acc[3] += pw*bfhi(u0.y);
        acc[4] += pw*bflo(u0.z); acc[5] += pw*bfhi(u0.z);
        acc[6] += pw*bflo(u0.w); acc[7] += pw*bfhi(u0.w);
      }
      if (v1) {
        float pw = s_p[w][eb + g4 + 1][hd8]; dsum += pw;
        acc[0] += pw*bflo(u1.x); acc[1] += pw*bfhi(u1.x);
        acc[2] += pw*bflo(u1.y); acc[3] += pw*bfhi(u1.y);
        acc[4] += pw*bflo(u1.z); acc[5] += pw*bfhi(u1.z);
        acc[6] += pw*bflo(u1.w); acc[7] += pw*bfhi(u1.w);
      }
      if (v2) {
        float pw = s_p[w][eb + g4 + 2][hd8]; dsum += pw;
        acc[0] += pw*bflo(u2.x); acc[1] += pw*bfhi(u2.x);
        acc[2] += pw*bflo(u2.y); acc[3] += pw*bfhi(u2.y);
        acc[4] += pw*bflo(u2.z); acc[5] += pw*bfhi(u2.z);
        acc[6] += pw*bflo(u2.w); acc[7] += pw*bfhi(u2.w);
      }
      if (v3) {
        float pw = s_p[w][eb + g4 + 3][hd8]; dsum += pw;
        acc[0] += pw*bflo(u3.x); acc[1] += pw*bfhi(u3.x);
        acc[2] += pw*bflo(u3.y); acc[3] += pw*bfhi(u3.y);
        acc[4] += pw*bflo(u3.z); acc[5] += pw*bfhi(u3.z);
        acc[6] += pw*bflo(u3.w); acc[7] += pw*bfhi(u3.w);
      }
      u0 = t0; u1 = t1; u2 = t2; u3 = t3;
      v0 = w0; v1 = w1; v2 = w2; v3 = w3;
    }
  }
  // each lane holds the full denominator for its head and 8 full channel sums
  float inv = 1.f / dsum;
  float4 b0 = ld4(&bias[c0]);
  float4 b1 = ld4(&bias[c0 + 4]);
  uint4 o;
  o.x = (unsigned)f2bf(fmaxf(acc[0]*inv + b0.x, 0.f))
      | ((unsigned)f2bf(fmaxf(acc[1]*inv + b0.y, 0.f)) << 16);
  o.y = (unsigned)f2bf(fmaxf(acc[2]*inv + b0.z, 0.f))
      | ((unsigned)f2bf(fmaxf(acc[3]*inv + b0.w, 0.f)) << 16);
  o.z = (unsigned)f2bf(fmaxf(acc[4]*inv + b1.x, 0.f))
      | ((unsigned)f2bf(fmaxf(acc[5]*inv + b1.y, 0.f)) << 16);
  o.w = (unsigned)f2bf(fmaxf(acc[6]*inv + b1.z, 0.f))
      | ((unsigned)f2bf(fmaxf(acc[7]*inv + b1.w, 0.f)) << 16);
  *(uint4*)&outbf[(size_t)n*HC + c0] = o;
}

// ---------------- fused MLP: out = relu(Cbf@W1+b1)@W2+b2, MFMA ----------------
__global__ __launch_bounds__(256) void k_mlp(const unsigned short* __restrict__ Cbf,
    const unsigned short* __restrict__ W1h, const unsigned short* __restrict__ W1l,
    const unsigned short* __restrict__ W2h, const unsigned short* __restrict__ W2l,
    const float* __restrict__ b1, const float* __restrict__ b2,
    float* __restrict__ out, int M) {
  __shared__ __align__(16) unsigned short Abuf[4096];   // 128 rows x 32 k (slot-swizzled)
  __shared__ __align__(16) unsigned short Hs[128*72];   // hid bf16, stride 72
  int t = threadIdx.x, lane = t & 63, w = t >> 6;
  int ln15 = lane & 15, lq = lane >> 4;
  int row0 = blockIdx.x * 128;

  f32x4 acc1[2][4];
  #pragma unroll
  for (int i=0;i<2;i++)
    #pragma unroll
    for (int j=0;j<4;j++) acc1[i][j] = (f32x4){0.f,0.f,0.f,0.f};

  int sA = w*64 + lane;
  int sB = 256 + w*64 + lane;
  int rA = sA >> 2, segA = (sA & 3) ^ ((rA >> 1) & 3);
  int rB = sB >> 2, segB = (sB & 3) ^ ((rB >> 1) & 3);
  size_t gA = (size_t)(row0 + rA) * 256 + segA*8;
  size_t gB = (size_t)(row0 + rB) * 256 + segB*8;
  int lA = (w*64)*8, lB = (256 + w*64)*8;

  for (int c = 0; c < 8; c++) {
    int k0 = c*32;
    dma16(Cbf + gA + k0, &Abuf[lA]);
    dma16(Cbf + gB + k0, &Abuf[lB]);
    __syncthreads();
    bf16x8 a[2];
    #pragma unroll
    for (int i = 0; i < 2; i++) {
      int r = w*32 + i*16 + ln15;
      int s = r*4 + (lq ^ ((r >> 1) & 3));
      a[i] = *(bf16x8*)&Abuf[s*8];
    }
    #pragma unroll
    for (int j = 0; j < 4; j++) {
      int n = j*16 + ln15;
      int k = k0 + lq*8;
      bf16x8 bh = *(const bf16x8*)&W1h[(size_t)n*256 + k];
      bf16x8 bl = *(const bf16x8*)&W1l[(size_t)n*256 + k];
      #pragma unroll
      for (int i = 0; i < 2; i++) {
        acc1[i][j] = __builtin_amdgcn_mfma_f32_16x16x32_bf16(a[i], bh, acc1[i][j], 0,0,0);
        acc1[i][j] = __builtin_amdgcn_mfma_f32_16x16x32_bf16(a[i], bl, acc1[i][j], 0,0,0);
      }
    }
    __syncthreads();
  }
  #pragma unroll
  for (int j = 0; j < 4; j++) {
    int col = j*16 + ln15;
    float bv = b1[col];
    #pragma unroll
    for (int i = 0; i < 2; i++) {
      #pragma unroll
      for (int r = 0; r < 4; r++) {
        int row = w*32 + i*16 + lq*4 + r;
        Hs[row*72 + col] = f2bf(fmaxf(acc1[i][j][r] + bv, 0.f));
      }
    }
  }
  f32x4 acc2[2][3];
  #pragma unroll
  for (int i=0;i<2;i++)
    #pragma unroll
    for (int j=0;j<3;j++) acc2[i][j] = (f32x4){0.f,0.f,0.f,0.f};
  #pragma unroll
  for (int kf = 0; kf < 2; kf++) {
    bf16x8 a2[2];
    #pragma unroll
    for (int i = 0; i < 2; i++) {
      int m = w*32 + i*16 + ln15;
      a2[i] = *(bf16x8*)&Hs[m*72 + kf*32 + lq*8];
    }
    #pragma unroll
    for (int j = 0; j < 3; j++) {
      int n = j*16 + ln15;
      int k = kf*32 + lq*8;
      bf16x8 wh = *(const bf16x8*)&W2h[(size_t)n*64 + k];
      bf16x8 wl = *(const bf16x8*)&W2l[(size_t)n*64 + k];
      #pragma unroll
      for (int i = 0; i < 2; i++) {
        acc2[i][j] = __builtin_amdgcn_mfma_f32_16x16x32_bf16(a2[i], wh, acc2[i][j], 0,0,0);
        acc2[i][j] = __builtin_amdgcn_mfma_f32_16x16x32_bf16(a2[i], wl, acc2[i][j], 0,0,0);
      }
    }
  }
  #pragma unroll
  for (int j = 0; j < 3; j++) {
    int col = j*16 + ln15;
    if (col < 40) {
      float bv = b2[col];
      #pragma unroll
      for (int i = 0; i < 2; i++) {
        #pragma unroll
        for (int r = 0; r < 4; r++) {
          int row = row0 + w*32 + i*16 + lq*4 + r;
          if (row < M) out[(size_t)row*40 + col] = acc2[i][j][r] + bv;
        }
      }
    }
  }
}

extern "C" void kernel_launch(void* const* d_in, const int* in_sizes, int n_in,
                              void* d_out, int out_size, void* d_ws, size_t ws_size,
                              hipStream_t stream) {
  const int Nn = in_sizes[0] / HC;   // 50000
  const int E  = in_sizes[1] / 2;    // 800000
  const int Mpad = (Nn + 127) & ~127;
  const float* x        = (const float*)d_in[0];
  const int*   ei       = (const int*)d_in[1];
  const float* W        = (const float*)d_in[2];
  const float* att_src  = (const float*)d_in[3];
  const float* att_dst  = (const float*)d_in[4];
  const float* biasconv = (const float*)d_in[5];
  const float* W1       = (const float*)d_in[6];
  const float* b1       = (const float*)d_in[7];
  const float* W2       = (const float*)d_in[8];
  const float* b2       = (const float*)d_in[9];
  float* out = (float*)d_out;

  size_t off = 0;
  auto alloc = [&](size_t bytes)->void* {
    void* p = (void*)((char*)d_ws + off);
    off += (bytes + 255) & ~(size_t)255;
    return p;
  };
  unsigned short* hbf = (unsigned short*)alloc((size_t)Nn*HC*sizeof(unsigned short));
  void* ublk = alloc((size_t)Mpad*HC*sizeof(float));
  unsigned short* Ahi = (unsigned short*)ublk;
  unsigned short* Alo = Ahi + (size_t)Mpad*HC;
  unsigned short* outc = (unsigned short*)ublk;    // aliases Ahi/Alo (disjoint lifetime)
  unsigned short* Bhi = (unsigned short*)alloc((size_t)256*256*sizeof(unsigned short));
  unsigned short* Blo = (unsigned short*)alloc((size_t)256*256*sizeof(unsigned short));
  unsigned short* W1h = (unsigned short*)alloc((size_t)64*256*sizeof(unsigned short));
  unsigned short* W1l = (unsigned short*)alloc((size_t)64*256*sizeof(unsigned short));
  unsigned short* W2h = (unsigned short*)alloc((size_t)48*64*sizeof(unsigned short));
  unsigned short* W2l = (unsigned short*)alloc((size_t)48*64*sizeof(unsigned short));
  float* a_src_v  = (float*)alloc((size_t)Nn*4*sizeof(float));
  float* a_dst_v  = (float*)alloc((size_t)Nn*4*sizeof(float));
  int*   count    = (int*)alloc((size_t)Nn*sizeof(int));
  int*   rowstart = (int*)alloc((size_t)(Nn+1)*sizeof(int));
  int*   cursor   = (int*)alloc((size_t)Nn*sizeof(int));
  int*   partial  = (int*)alloc(256*sizeof(int));
  int*   csr      = (int*)alloc((size_t)(E+Nn)*sizeof(int));
  (void)ws_size; (void)n_in; (void)out_size;

  dim3 blk(256);
  int nf4 = Nn*64;
  int nSplit = (nf4 + 255)/256;
  int nCnt = (E + 255)/256;
  int nb = (Nn + 255)/256;
  int nGemm = 2 * (Mpad/128);

  hipMemsetAsync(count, 0, (size_t)Nn*sizeof(int), stream);
  k_pre<<<dim3(nSplit + 368 + nCnt), blk, 0, stream>>>(x, W, W1, W2,
      Ahi, Alo, Bhi, Blo, W1h, W1l, W2h, W2l, ei, count, nf4, E, nSplit);
  k_gemmscan<<<dim3(nGemm + nb), blk, 0, stream>>>(Ahi, Alo, Bhi, Blo, hbf,
      att_src, att_dst, a_src_v, a_dst_v, Nn, nGemm, count, rowstart, partial, Nn);
  k_scan23<<<dim3(nb), blk, 0, stream>>>(rowstart, cursor, partial, count, Nn, nb);
  k_fill<<<dim3((E+Nn+255)/256), blk, 0, stream>>>(ei, cursor, csr, E, Nn);
  k_gat<<<dim3(Nn/8), blk, 0, stream>>>(hbf, (const float4*)a_src_v, (const float4*)a_dst_v,
                                        rowstart, csr, biasconv, outc);
  k_mlp<<<dim3(Mpad/128), blk, 0, stream>>>(outc, W1h, W1l, W2h, W2l, b1, b2, out, Nn);
}